// Round 1
// baseline (692.650 us; speedup 1.0000x reference)
//
#include <hip/hip_runtime.h>
#include <hip/hip_bf16.h>
#include <stdint.h>

typedef unsigned int uint;
typedef unsigned long long ull;

#define NPRE   6000
#define NPOST  1000
#define NWORDS 94          // ceil(6000/64)
#define EQCAP  32768
#define IMG_W  1216.0f
#define IMG_H  800.0f

// ---------- workspace layout (bytes) ----------
#define WS_KEYS    0            // uint[2M]                8,000,000
#define WS_HIST    8000000      // uint[4*256]             4,096
#define WS_STATE   8004096      // uint[16]
#define WS_SEL     8004160      // int[6016]
#define WS_EQ      8028224      // int[32768]
#define WS_K64     8159296      // ull[6016]
#define WS_BOXES   8207424      // float4[6016]
#define WS_SORTED  8303680      // float4[6016]
#define WS_AREAS   8399936      // float[6016]
#define WS_MASK    8424000      // ull[6016*94]            4,524,032

// state indices: 0=prefix P, 1=remaining rank r, 2=sel_count, 3=eq_count, 4=T32, 5=ne

// correctly-rounded f32 exp via double (glibc expf is CR; best first guess for the np ref)
__device__ __forceinline__ float exp_ref(float x) { return (float)exp((double)x); }

__device__ __forceinline__ float sigmoid_ref(float x) {
#pragma clang fp contract(off)
    float e = exp_ref(-x);
    float d = 1.0f + e;
    return 1.0f / d;
}

__device__ __forceinline__ bool decode_box(float4 a, float4 d,
                                           float& x1, float& y1, float& x2, float& y2) {
#pragma clang fp contract(off)
    float wa = a.z - a.x;
    float ha = a.w - a.y;
    float xa = a.x + 0.5f * wa;
    float ya = a.y + 0.5f * ha;
    float x  = d.x * wa + xa;
    float y  = d.y * ha + ya;
    float w  = exp_ref(d.z) * wa;
    float h  = exp_ref(d.w) * ha;
    x1 = fminf(fmaxf(x - 0.5f * w, 0.0f), IMG_W - 1.0f);
    y1 = fminf(fmaxf(y - 0.5f * h, 0.0f), IMG_H - 1.0f);
    x2 = fminf(fmaxf(x + 0.5f * w, 0.0f), IMG_W - 1.0f);
    y2 = fminf(fmaxf(y + 0.5f * h, 0.0f), IMG_H - 1.0f);
    return (x2 - x1 >= 16.0f) && (y2 - y1 >= 16.0f);
}

__global__ void k_init(uint* hist, uint* state) {
    int t = blockIdx.x * blockDim.x + threadIdx.x;
    if (t < 1024) hist[t] = 0;
    if (t == 0) {
        state[0] = 0;       // prefix
        state[1] = NPRE;    // remaining rank
        state[2] = 0;       // sel_count
        state[3] = 0;       // eq_count
        state[4] = 0;       // T32
        state[5] = 0;       // ne
    }
}

__global__ void k_decode(const float4* __restrict__ A, const float4* __restrict__ D,
                         const float* __restrict__ L, uint* __restrict__ keys, int N) {
    int i = blockIdx.x * blockDim.x + threadIdx.x;
    if (i >= N) return;
    float x1, y1, x2, y2;
    bool ok = decode_box(A[i], D[i], x1, y1, x2, y2);
    uint key = 0u;
    if (ok) {
        float s = sigmoid_ref(L[i]);           // s in (0,1] -> positive float
        key = __float_as_uint(s) | 0x80000000u; // monotone map, invalid(0) < any valid
    }
    keys[i] = key;
}

__global__ void k_hist(const uint* __restrict__ keys, int N,
                       const uint* __restrict__ state, uint* __restrict__ hist, int k) {
    __shared__ uint lh[256];
    if (threadIdx.x < 256) lh[threadIdx.x] = 0;
    __syncthreads();
    uint P = state[0];
    int shift = (k + 1) * 8;
    for (int i = blockIdx.x * blockDim.x + threadIdx.x; i < N; i += gridDim.x * blockDim.x) {
        uint key = keys[i];
        bool m = (k == 3) || ((key >> shift) == (P >> shift));
        if (m) atomicAdd(&lh[(key >> (k * 8)) & 0xFFu], 1u);
    }
    __syncthreads();
    if (threadIdx.x < 256) {
        uint v = lh[threadIdx.x];
        if (v) atomicAdd(&hist[threadIdx.x], v);
    }
}

__global__ void k_scan(uint* state, const uint* hist, int k) {
    uint r = state[1];
    uint P = state[0];
    uint cum = 0;
    int b = 255;
    for (; b >= 0; --b) {
        uint h = hist[b];
        if (cum + h >= r) break;
        cum += h;
    }
    if (b < 0) b = 0; // should not happen
    state[0] = P | ((uint)b << (k * 8));
    state[1] = r - cum;
    if (k == 0) { state[4] = state[0]; state[5] = state[1]; }
}

__global__ void k_compact(const uint* __restrict__ keys, int N, uint* state,
                          int* __restrict__ sel, int* __restrict__ eq) {
    int i = blockIdx.x * blockDim.x + threadIdx.x;
    if (i >= N) return;
    uint T = state[4];
    uint key = keys[i];
    if (key > T) {
        sel[atomicAdd(&state[2], 1u)] = i;
    } else if (key == T && T != 0u) {
        uint p = atomicAdd(&state[3], 1u);
        if (p < EQCAP) eq[p] = i;
    }
}

__global__ void k_eqsel(uint* state, const int* __restrict__ eq, int* __restrict__ sel) {
    int ne = (int)state[5];
    int e  = (int)min(state[3], (uint)EQCAP);
    if (ne <= 0) return;
    for (int i = threadIdx.x; i < e; i += blockDim.x) {
        int idx = eq[i];
        int rank = 0;
        for (int j = 0; j < e; ++j) rank += (eq[j] < idx);
        if (rank < ne) sel[atomicAdd(&state[2], 1u)] = idx;
    }
}

__global__ void k_gather(const float4* __restrict__ A, const float4* __restrict__ D,
                         const float* __restrict__ L, const int* __restrict__ sel,
                         ull* __restrict__ K64, float4* __restrict__ boxes) {
    int i = blockIdx.x * blockDim.x + threadIdx.x;
    if (i >= NPRE) return;
    int idx = sel[i];
    float x1, y1, x2, y2;
    decode_box(A[idx], D[idx], x1, y1, x2, y2);
    float s = sigmoid_ref(L[idx]);
    uint key = __float_as_uint(s) | 0x80000000u;
    K64[i] = ((ull)key << 32) | (uint)(~(uint)idx); // bigger = better (score desc, idx asc)
    boxes[i] = make_float4(x1, y1, x2, y2);
}

__global__ void k_ranksort(const ull* __restrict__ K64, const float4* __restrict__ boxes,
                           float4* __restrict__ sorted, float* __restrict__ areas) {
    __shared__ ull tile[256];
    int i = blockIdx.x * blockDim.x + threadIdx.x;
    ull mine = (i < NPRE) ? K64[i] : 0ull;
    int rank = 0;
    for (int base = 0; base < NPRE; base += 256) {
        int j = base + threadIdx.x;
        tile[threadIdx.x] = (j < NPRE) ? K64[j] : 0ull;
        __syncthreads();
        int lim = min(256, NPRE - base);
        for (int t = 0; t < lim; ++t) rank += (tile[t] > mine);
        __syncthreads();
    }
    if (i < NPRE) {
#pragma clang fp contract(off)
        float4 b = boxes[i];
        sorted[rank] = b;
        areas[rank] = (b.z - b.x) * (b.w - b.y);
    }
}

__global__ __launch_bounds__(64) void k_mask(const float4* __restrict__ sorted,
                                             const float* __restrict__ areas,
                                             ull* __restrict__ mask) {
#pragma clang fp contract(off)
    __shared__ float4 cb[64];
    __shared__ float  ca[64];
    int cw = blockIdx.x;  // col word
    int rc = blockIdx.y;  // row chunk
    int t  = threadIdx.x;
    int col = cw * 64 + t;
    if (col < NPRE) { cb[t] = sorted[col]; ca[t] = areas[col]; }
    else            { cb[t] = make_float4(0.f, 0.f, 0.f, 0.f); ca[t] = 0.f; }
    __syncthreads();
    int row = rc * 64 + t;
    if (row >= NPRE) return;
    float4 rb = sorted[row];
    float  ra = areas[row];
    ull bits = 0;
    for (int j = 0; j < 64; ++j) {
        float xx1 = fmaxf(rb.x, cb[j].x);
        float yy1 = fmaxf(rb.y, cb[j].y);
        float xx2 = fminf(rb.z, cb[j].z);
        float yy2 = fminf(rb.w, cb[j].w);
        float inter = fmaxf(xx2 - xx1, 0.0f) * fmaxf(yy2 - yy1, 0.0f);
        float uni = ra + ca[j] - inter;   // (ra + ca) - inter, same as reference
        float iou = inter / uni;
        if (iou > 0.7f) bits |= (1ull << j);  // suppress iff !(iou <= 0.7)
    }
    mask[(size_t)row * NWORDS + cw] = bits;
}

__device__ __forceinline__ ull shfl64(ull v, int lane) {
    int lo = __shfl((int)(v & 0xffffffffull), lane, 64);
    int hi = __shfl((int)(v >> 32), lane, 64);
    return ((ull)(uint)hi << 32) | (uint)lo;
}

__global__ __launch_bounds__(64) void k_nms(const ull* __restrict__ mask,
                                            const float4* __restrict__ sorted,
                                            float* __restrict__ out) {
    int lane = threadIdx.x;
    __shared__ int keepLDS[NPOST];
    // removed mask in registers: lane owns word `lane` (rem0) and word `64+lane` (rem1, lane<30)
    ull rem0 = 0, rem1 = 0;
    if (lane == NWORDS - 1 - 64) rem1 = 0xFFFF000000000000ull; // word 93: rows 6000..6015 invalid
    int kc = 0;
    for (int c = 0; c < NWORDS && kc < NPOST; ++c) {
        ull rm = (c < 64) ? shfl64(rem0, c) : shfl64(rem1, c - 64);
        ull alive = ~rm;
        int rowbase = c * 64;
        int myrow = rowbase + lane;
        ull intraw = 0;
        if (myrow < NPRE) intraw = mask[(size_t)myrow * NWORDS + c];
        ull keptbits = 0;
        while (alive && kc < NPOST) {
            int j = __builtin_ctzll(alive);
            keptbits |= (1ull << j);
            if (lane == 0) keepLDS[kc] = rowbase + j;
            kc++;
            ull mrow = shfl64(intraw, j);
            alive &= ~mrow;
            alive &= ~(1ull << j);
        }
        // apply kept rows' suppression to this lane's owned words
        ull kb = keptbits;
        while (kb) {
            int j = __builtin_ctzll(kb);
            kb &= kb - 1;
            size_t rbase = (size_t)(rowbase + j) * NWORDS;
            rem0 |= mask[rbase + lane];
            if (lane < NWORDS - 64) rem1 |= mask[rbase + 64 + lane];
        }
    }
    __syncthreads();
    for (int r = lane; r < NPOST; r += 64) {
        float4 b = make_float4(0.f, 0.f, 0.f, 0.f);
        if (r < kc) b = sorted[keepLDS[r]];
        reinterpret_cast<float4*>(out)[r] = b;
    }
}

extern "C" void kernel_launch(void* const* d_in, const int* in_sizes, int n_in,
                              void* d_out, int out_size, void* d_ws, size_t ws_size,
                              hipStream_t stream) {
    const float4* A = (const float4*)d_in[2];   // anchors (N,4)
    const float4* D = (const float4*)d_in[3];   // bbox_deltas (N,4)
    const float*  L = (const float*)d_in[4];    // logits (N,1)
    int N = in_sizes[4];

    char* ws = (char*)d_ws;
    uint*   keys   = (uint*)(ws + WS_KEYS);
    uint*   hist   = (uint*)(ws + WS_HIST);
    uint*   state  = (uint*)(ws + WS_STATE);
    int*    sel    = (int*)(ws + WS_SEL);
    int*    eq     = (int*)(ws + WS_EQ);
    ull*    K64    = (ull*)(ws + WS_K64);
    float4* boxes  = (float4*)(ws + WS_BOXES);
    float4* sorted = (float4*)(ws + WS_SORTED);
    float*  areas  = (float*)(ws + WS_AREAS);
    ull*    mask   = (ull*)(ws + WS_MASK);
    float*  out    = (float*)d_out;

    int nblk = (N + 255) / 256;

    k_init<<<4, 256, 0, stream>>>(hist, state);
    k_decode<<<nblk, 256, 0, stream>>>(A, D, L, keys, N);
    for (int k = 3; k >= 0; --k) {
        k_hist<<<1024, 256, 0, stream>>>(keys, N, state, hist + k * 256, k);
        k_scan<<<1, 1, 0, stream>>>(state, hist + k * 256, k);
    }
    k_compact<<<nblk, 256, 0, stream>>>(keys, N, state, sel, eq);
    k_eqsel<<<1, 256, 0, stream>>>(state, eq, sel);
    k_gather<<<(NPRE + 255) / 256, 256, 0, stream>>>(A, D, L, sel, K64, boxes);
    k_ranksort<<<(NPRE + 255) / 256, 256, 0, stream>>>(K64, boxes, sorted, areas);
    k_mask<<<dim3(NWORDS, NWORDS), 64, 0, stream>>>(sorted, areas, mask);
    k_nms<<<1, 64, 0, stream>>>(mask, sorted, out);
}

// Round 2
// 412.406 us; speedup vs baseline: 1.6795x; 1.6795x over previous
//
#include <hip/hip_runtime.h>
#include <hip/hip_bf16.h>
#include <stdint.h>

typedef unsigned int uint;
typedef unsigned long long ull;

#define NPRE   6000
#define NPOST  1000
#define NWORDS 94          // ceil(6000/64)
#define EQCAP  32768
#define IMG_W  1216.0f
#define IMG_H  800.0f

// ---------- workspace layout (bytes) ----------
#define WS_KEYS    0            // uint[2M]                8,000,000
#define WS_HIST    8000000      // uint[4*256]             4,096
#define WS_STATE   8004096      // uint[16]
#define WS_SEL     8004160      // int[6016]
#define WS_EQ      8028224      // int[32768]
#define WS_K64     8159296      // ull[6016]
#define WS_BOXES   8207424      // float4[6016]
#define WS_SORTED  8303680      // float4[6016]
#define WS_AREAS   8399936      // float[6016]
#define WS_MASK    8424000      // ull[6016*94]            4,524,032

// state indices: 0=prefix P, 1=remaining rank r, 2=sel_count, 3=eq_count, 4=T32, 5=ne

// correctly-rounded f32 exp via double (matches np ref: absmax 0.0 in R1)
__device__ __forceinline__ float exp_ref(float x) { return (float)exp((double)x); }

__device__ __forceinline__ float sigmoid_ref(float x) {
#pragma clang fp contract(off)
    float e = exp_ref(-x);
    float d = 1.0f + e;
    return 1.0f / d;
}

__device__ __forceinline__ bool decode_box(float4 a, float4 d,
                                           float& x1, float& y1, float& x2, float& y2) {
#pragma clang fp contract(off)
    float wa = a.z - a.x;
    float ha = a.w - a.y;
    float xa = a.x + 0.5f * wa;
    float ya = a.y + 0.5f * ha;
    float x  = d.x * wa + xa;
    float y  = d.y * ha + ya;
    float w  = exp_ref(d.z) * wa;
    float h  = exp_ref(d.w) * ha;
    x1 = fminf(fmaxf(x - 0.5f * w, 0.0f), IMG_W - 1.0f);
    y1 = fminf(fmaxf(y - 0.5f * h, 0.0f), IMG_H - 1.0f);
    x2 = fminf(fmaxf(x + 0.5f * w, 0.0f), IMG_W - 1.0f);
    y2 = fminf(fmaxf(y + 0.5f * h, 0.0f), IMG_H - 1.0f);
    return (x2 - x1 >= 16.0f) && (y2 - y1 >= 16.0f);
}

__global__ void k_init(uint* hist, uint* state) {
    int t = blockIdx.x * blockDim.x + threadIdx.x;
    if (t < 1024) hist[t] = 0;
    if (t == 0) {
        state[0] = 0;       // prefix
        state[1] = NPRE;    // remaining rank
        state[2] = 0;       // sel_count
        state[3] = 0;       // eq_count
        state[4] = 0;       // T32
        state[5] = 0;       // ne
    }
}

__global__ void k_decode(const float4* __restrict__ A, const float4* __restrict__ D,
                         const float* __restrict__ L, uint* __restrict__ keys, int N) {
    int i = blockIdx.x * blockDim.x + threadIdx.x;
    if (i >= N) return;
    float x1, y1, x2, y2;
    bool ok = decode_box(A[i], D[i], x1, y1, x2, y2);
    uint key = 0u;
    if (ok) {
        float s = sigmoid_ref(L[i]);           // s in (0,1] -> positive float
        key = __float_as_uint(s) | 0x80000000u; // monotone map, invalid(0) < any valid
    }
    keys[i] = key;
}

__global__ void k_hist(const uint* __restrict__ keys, int N,
                       const uint* __restrict__ state, uint* __restrict__ hist, int k) {
    __shared__ uint lh[256];
    if (threadIdx.x < 256) lh[threadIdx.x] = 0;
    __syncthreads();
    uint P = state[0];
    int shift = (k + 1) * 8;
    for (int i = blockIdx.x * blockDim.x + threadIdx.x; i < N; i += gridDim.x * blockDim.x) {
        uint key = keys[i];
        bool m = (k == 3) || ((key >> shift) == (P >> shift));
        if (m) atomicAdd(&lh[(key >> (k * 8)) & 0xFFu], 1u);
    }
    __syncthreads();
    if (threadIdx.x < 256) {
        uint v = lh[threadIdx.x];
        if (v) atomicAdd(&hist[threadIdx.x], v);
    }
}

// parallel scan: 256 threads, inclusive suffix sums in LDS, unique winner writes state
__global__ void k_scan(uint* state, const uint* __restrict__ hist, int k) {
    __shared__ uint S[256];
    int t = threadIdx.x;
    S[t] = hist[t];
    __syncthreads();
    for (int off = 1; off < 256; off <<= 1) {
        uint v = S[t] + ((t + off < 256) ? S[t + off] : 0u);
        __syncthreads();
        S[t] = v;
        __syncthreads();
    }
    uint r = state[1];
    uint Sincl = S[t];
    uint Sexcl = (t < 255) ? S[t + 1] : 0u;
    if (Sincl >= r && Sexcl < r) {   // exactly one thread (requires hist[t] > 0)
        uint P = state[0];
        uint newP = P | ((uint)t << (k * 8));
        state[0] = newP;
        state[1] = r - Sexcl;
        if (k == 0) { state[4] = newP; state[5] = r - Sexcl; }
    }
}

__global__ void k_compact(const uint* __restrict__ keys, int N, uint* state,
                          int* __restrict__ sel, int* __restrict__ eq) {
    int i = blockIdx.x * blockDim.x + threadIdx.x;
    if (i >= N) return;
    uint T = state[4];
    uint key = keys[i];
    if (key > T) {
        sel[atomicAdd(&state[2], 1u)] = i;
    } else if (key == T && T != 0u) {
        uint p = atomicAdd(&state[3], 1u);
        if (p < EQCAP) eq[p] = i;
    }
}

__global__ void k_eqsel(uint* state, const int* __restrict__ eq, int* __restrict__ sel) {
    int ne = (int)state[5];
    int e  = (int)min(state[3], (uint)EQCAP);
    if (ne <= 0) return;
    for (int i = threadIdx.x; i < e; i += blockDim.x) {
        int idx = eq[i];
        int rank = 0;
        for (int j = 0; j < e; ++j) rank += (eq[j] < idx);
        if (rank < ne) sel[atomicAdd(&state[2], 1u)] = idx;
    }
}

__global__ void k_gather(const float4* __restrict__ A, const float4* __restrict__ D,
                         const float* __restrict__ L, const int* __restrict__ sel,
                         ull* __restrict__ K64, float4* __restrict__ boxes) {
    int i = blockIdx.x * blockDim.x + threadIdx.x;
    if (i >= NPRE) return;
    int idx = sel[i];
    float x1, y1, x2, y2;
    decode_box(A[idx], D[idx], x1, y1, x2, y2);
    float s = sigmoid_ref(L[idx]);
    uint key = __float_as_uint(s) | 0x80000000u;
    K64[i] = ((ull)key << 32) | (uint)(~(uint)idx); // bigger = better (score desc, idx asc)
    boxes[i] = make_float4(x1, y1, x2, y2);
}

__global__ void k_ranksort(const ull* __restrict__ K64, const float4* __restrict__ boxes,
                           float4* __restrict__ sorted, float* __restrict__ areas) {
    __shared__ ull tile[256];
    int i = blockIdx.x * blockDim.x + threadIdx.x;
    ull mine = (i < NPRE) ? K64[i] : 0ull;
    int rank = 0;
    for (int base = 0; base < NPRE; base += 256) {
        int j = base + threadIdx.x;
        tile[threadIdx.x] = (j < NPRE) ? K64[j] : 0ull;
        __syncthreads();
        int lim = min(256, NPRE - base);
        for (int t = 0; t < lim; ++t) rank += (tile[t] > mine);
        __syncthreads();
    }
    if (i < NPRE) {
#pragma clang fp contract(off)
        float4 b = boxes[i];
        sorted[rank] = b;
        areas[rank] = (b.z - b.x) * (b.w - b.y);
    }
}

__global__ __launch_bounds__(64) void k_mask(const float4* __restrict__ sorted,
                                             const float* __restrict__ areas,
                                             ull* __restrict__ mask) {
#pragma clang fp contract(off)
    int cw = blockIdx.x;  // col word
    int rc = blockIdx.y;  // row chunk
    if (cw < rc) return;  // NMS only reads words w >= row/64 (diag for intraw, w>c for rem)
    __shared__ float4 cb[64];
    __shared__ float  ca[64];
    int t = threadIdx.x;
    int col = cw * 64 + t;
    if (col < NPRE) { cb[t] = sorted[col]; ca[t] = areas[col]; }
    else            { cb[t] = make_float4(0.f, 0.f, 0.f, 0.f); ca[t] = 0.f; }
    __syncthreads();
    int row = rc * 64 + t;
    if (row >= NPRE) return;
    float4 rb = sorted[row];
    float  ra = areas[row];
    ull bits = 0;
    for (int j = 0; j < 64; ++j) {
        float xx1 = fmaxf(rb.x, cb[j].x);
        float yy1 = fmaxf(rb.y, cb[j].y);
        float xx2 = fminf(rb.z, cb[j].z);
        float yy2 = fminf(rb.w, cb[j].w);
        float inter = fmaxf(xx2 - xx1, 0.0f) * fmaxf(yy2 - yy1, 0.0f);
        float uni = ra + ca[j] - inter;   // (ra + ca) - inter, same as reference
        float iou = inter / uni;
        if (iou > 0.7f) bits |= (1ull << j);  // suppress iff !(iou <= 0.7)
    }
    mask[(size_t)row * NWORDS + cw] = bits;
}

__device__ __forceinline__ ull shfl64(ull v, int lane) {
    int lo = __shfl((int)(v & 0xffffffffull), lane, 64);
    int hi = __shfl((int)(v >> 32), lane, 64);
    return ((ull)(uint)hi << 32) | (uint)lo;
}

// cooperative NMS scan: wave 0 does the serial per-chunk pick (registers+shfl only),
// all 1024 threads apply kept rows' suppression masks (independent L2 loads -> LDS atomicOr)
__global__ __launch_bounds__(1024) void k_nms(const ull* __restrict__ mask,
                                              const float4* __restrict__ sorted,
                                              float* __restrict__ out) {
    int tid  = threadIdx.x;
    int lane = tid & 63;
    int wave = tid >> 6;
    __shared__ uint rem32[2 * NWORDS];
    __shared__ int  keepLDS[NPOST];
    __shared__ int  chunkKept[64];
    __shared__ int  chunkCount;
    __shared__ int  kcShared;
    for (int w = tid; w < 2 * NWORDS; w += 1024) rem32[w] = 0;
    if (tid == 0) rem32[2 * (NWORDS - 1) + 1] = 0xFFFF0000u; // rows 6000..6015 invalid
    __syncthreads();
    int kc = 0;
    for (int c = 0; c < NWORDS; ++c) {
        if (wave == 0) {
            int rowbase = c * 64;
            int myrow = rowbase + lane;
            ull intraw = (myrow < NPRE) ? mask[(size_t)myrow * NWORDS + c] : 0ull;
            ull rm = ((ull)rem32[2 * c + 1] << 32) | (ull)rem32[2 * c];
            ull alive = ~rm;
            int n = 0;
            while (alive && kc < NPOST) {
                int j = __builtin_ctzll(alive);
                if (lane == 0) { keepLDS[kc] = rowbase + j; chunkKept[n] = rowbase + j; }
                n++; kc++;
                ull mrow = shfl64(intraw, j);
                alive &= ~mrow;
                alive &= ~(1ull << j);
            }
            if (lane == 0) { chunkCount = n; kcShared = kc; }
        }
        __syncthreads();
        int nk    = chunkCount;
        int kcAll = kcShared;
        kc = kcAll;
        if (kcAll >= NPOST) break;
        int nw = NWORDS - 1 - c;          // only future words matter
        int pairs = nk * nw;
        for (int p = tid; p < pairs; p += 1024) {
            int k = p / nw;
            int w = c + 1 + (p - k * nw);
            ull m = mask[(size_t)chunkKept[k] * NWORDS + w];
            uint lo = (uint)m, hi = (uint)(m >> 32);
            if (lo) atomicOr(&rem32[2 * w],     lo);
            if (hi) atomicOr(&rem32[2 * w + 1], hi);
        }
        __syncthreads();
    }
    __syncthreads();
    int kcAll = kcShared;
    for (int r = tid; r < NPOST; r += 1024) {
        float4 b = make_float4(0.f, 0.f, 0.f, 0.f);
        if (r < kcAll) b = sorted[keepLDS[r]];
        reinterpret_cast<float4*>(out)[r] = b;
    }
}

extern "C" void kernel_launch(void* const* d_in, const int* in_sizes, int n_in,
                              void* d_out, int out_size, void* d_ws, size_t ws_size,
                              hipStream_t stream) {
    const float4* A = (const float4*)d_in[2];   // anchors (N,4)
    const float4* D = (const float4*)d_in[3];   // bbox_deltas (N,4)
    const float*  L = (const float*)d_in[4];    // logits (N,1)
    int N = in_sizes[4];

    char* ws = (char*)d_ws;
    uint*   keys   = (uint*)(ws + WS_KEYS);
    uint*   hist   = (uint*)(ws + WS_HIST);
    uint*   state  = (uint*)(ws + WS_STATE);
    int*    sel    = (int*)(ws + WS_SEL);
    int*    eq     = (int*)(ws + WS_EQ);
    ull*    K64    = (ull*)(ws + WS_K64);
    float4* boxes  = (float4*)(ws + WS_BOXES);
    float4* sorted = (float4*)(ws + WS_SORTED);
    float*  areas  = (float*)(ws + WS_AREAS);
    ull*    mask   = (ull*)(ws + WS_MASK);
    float*  out    = (float*)d_out;

    int nblk = (N + 255) / 256;

    k_init<<<4, 256, 0, stream>>>(hist, state);
    k_decode<<<nblk, 256, 0, stream>>>(A, D, L, keys, N);
    for (int k = 3; k >= 0; --k) {
        k_hist<<<1024, 256, 0, stream>>>(keys, N, state, hist + k * 256, k);
        k_scan<<<1, 256, 0, stream>>>(state, hist + k * 256, k);
    }
    k_compact<<<nblk, 256, 0, stream>>>(keys, N, state, sel, eq);
    k_eqsel<<<1, 256, 0, stream>>>(state, eq, sel);
    k_gather<<<(NPRE + 255) / 256, 256, 0, stream>>>(A, D, L, sel, K64, boxes);
    k_ranksort<<<(NPRE + 255) / 256, 256, 0, stream>>>(K64, boxes, sorted, areas);
    k_mask<<<dim3(NWORDS, NWORDS), 64, 0, stream>>>(sorted, areas, mask);
    k_nms<<<1, 1024, 0, stream>>>(mask, sorted, out);
}